// Round 3
// baseline (248.559 us; speedup 1.0000x reference)
//
#include <hip/hip_runtime.h>
#include <hip/hip_bf16.h>
#include <stdint.h>

#define N_ROWS 16384

typedef __bf16 bf16x8 __attribute__((ext_vector_type(8)));
typedef float f32x4 __attribute__((ext_vector_type(4)));

#define AS1 __attribute__((address_space(1)))
#define AS3 __attribute__((address_space(3)))

// ---------------- ws layout (bytes) ----------------
// WcS : (W_token@W_qkv)^T bf16 [384][768], 8-elt chunks XOR-swizzled   589824
// bc  : f32 [384]  (b_token@W_qkv + b_qkv)                               1536
// qb  : bf16 [16384][128]  (q * -log2e)                               4194304
// kb  : bf16 [16384][128]  (LINEAR now - read direct from L2)         4194304
// wv  : f32  [16384]  ((v+bias) . W_fc)                                 65536
// part: f32  [8][16384]                                                524288
#define OFF_WCS  0u
#define OFF_BC   589824u
#define OFF_QB   591360u
#define OFF_KB   4785664u
#define OFF_WV   8979968u
#define OFF_PART 9045504u

// ---- kernel 0: Wc = W_token @ W_qkv -> bf16, [n][768] with 8-elt chunk XOR swizzle;
//      bc = b_token @ W_qkv + b_qkv ----
__global__ void prep(const float* __restrict__ Wt, const float* __restrict__ Wq,
                     const float* __restrict__ bt, const float* __restrict__ bq,
                     __bf16* __restrict__ WcS, float* __restrict__ bc) {
    int u = blockIdx.x * 256 + threadIdx.x;          // [0, 768*96)
    if (u < 768 * 96) {
        int k = u / 96, n4 = u % 96;
        float s[4] = {0, 0, 0, 0};
        const float* wtp = Wt + k * 128;
        const float* wqp = Wq + n4 * 4;
#pragma unroll 8
        for (int d = 0; d < 128; d++) {
            float a = wtp[d];
            float4 b = *(const float4*)(wqp + d * 384);
            s[0] += a * b.x; s[1] += a * b.y; s[2] += a * b.z; s[3] += a * b.w;
        }
        int kb_ = k >> 6, c = (k >> 3) & 7, k7 = k & 7;
#pragma unroll
        for (int j = 0; j < 4; j++) {
            int n = n4 * 4 + j;
            WcS[n * 768 + kb_ * 64 + ((c ^ (n & 7)) << 3) + k7] = (__bf16)s[j];
        }
    }
    if (u < 384) {
        float s = bq[u];
        for (int d = 0; d < 128; d++) s += bt[d] * Wq[d * 384 + u];
        bc[u] = s;
    }
}

// ---- kernel 1: qkv = bf16(x) @ Wc + bc via LDS-staged tiled GEMM ----
// BM=64, BN=128, BK=64; grid (256, 3); sp aligns with q / k / v+wv epilogues.
__launch_bounds__(256)
__global__ void gemm_qkv(const float* __restrict__ x, const __bf16* __restrict__ WcS,
                         const float* __restrict__ bc, const float* __restrict__ W_fc,
                         __bf16* __restrict__ qb, __bf16* __restrict__ kb,
                         float* __restrict__ wv) {
    __shared__ float  Asm[64 * 64];    // fp32 A tile, 32B-pair XOR-swizzled
    __shared__ __bf16 Bsm[128 * 64];   // bf16 B tile, 16B-chunk XOR-swizzled
    __shared__ float  wred[64];
    const int tid = threadIdx.x, wave = tid >> 6, lane = tid & 63;
    const int n16 = lane & 15, q = lane >> 4;
    const int mh = wave >> 1, nw = wave & 1;
    const int row0 = blockIdx.x * 64;
    const int sp = blockIdx.y;

    // per-lane staging source pointers (swizzle baked into the global address)
    const char* aptr[4];
    const char* bptr[4];
    {
        int p = (lane & 15) >> 1, half = lane & 1;
#pragma unroll
        for (int i = 0; i < 4; i++) {
            int ar = row0 + wave * 16 + i * 4 + (lane >> 4);
            aptr[i] = (const char*)x + (size_t)ar * 3072 + ((p ^ (ar & 7)) * 8 + half * 4) * 4;
            int br = sp * 128 + wave * 32 + i * 8 + (lane >> 3);
            bptr[i] = (const char*)WcS + (size_t)br * 1536 + (lane & 7) * 16;
        }
    }
    f32x4 acc[2][4];
#pragma unroll
    for (int mt = 0; mt < 2; mt++)
#pragma unroll
        for (int t = 0; t < 4; t++) acc[mt][t] = (f32x4){0, 0, 0, 0};

    for (int kbi = 0; kbi < 12; kbi++) {
#pragma unroll
        for (int i = 0; i < 4; i++)
            __builtin_amdgcn_global_load_lds((const AS1 void*)(aptr[i] + kbi * 256),
                (AS3 void*)((char*)Asm + wave * 4096 + i * 1024), 16, 0, 0);
#pragma unroll
        for (int i = 0; i < 4; i++)
            __builtin_amdgcn_global_load_lds((const AS1 void*)(bptr[i] + kbi * 128),
                (AS3 void*)((char*)Bsm + wave * 4096 + i * 1024), 16, 0, 0);
        __syncthreads();
#pragma unroll
        for (int ks = 0; ks < 2; ks++) {
            const int swz = ((ks * 4 + q) ^ (n16 & 7)) << 3;
            bf16x8 af[2];
#pragma unroll
            for (int mt = 0; mt < 2; mt++) {
                const float* ap = Asm + (mh * 32 + mt * 16 + n16) * 64 + swz;
                f32x4 a0 = *(const f32x4*)ap;
                f32x4 a1 = *(const f32x4*)(ap + 4);
                bf16x8 t;
                t[0] = (__bf16)a0[0]; t[1] = (__bf16)a0[1]; t[2] = (__bf16)a0[2]; t[3] = (__bf16)a0[3];
                t[4] = (__bf16)a1[0]; t[5] = (__bf16)a1[1]; t[6] = (__bf16)a1[2]; t[7] = (__bf16)a1[3];
                af[mt] = t;
            }
#pragma unroll
            for (int t = 0; t < 4; t++) {
                bf16x8 bf = *(const bf16x8*)(Bsm + (nw * 64 + t * 16 + n16) * 64 + swz);
                acc[0][t] = __builtin_amdgcn_mfma_f32_16x16x32_bf16(af[0], bf, acc[0][t], 0, 0, 0);
                acc[1][t] = __builtin_amdgcn_mfma_f32_16x16x32_bf16(af[1], bf, acc[1][t], 0, 0, 0);
            }
        }
        __syncthreads();
    }

    // epilogue: cols of this block = sp*128 + nw*64 + t*16 + n16
    const int clb = nw * 64 + n16;
    if (sp == 0) {
#pragma unroll
        for (int t = 0; t < 4; t++) {
            int cl = clb + t * 16;
            float bcv = bc[cl];
#pragma unroll
            for (int mt = 0; mt < 2; mt++)
#pragma unroll
                for (int r = 0; r < 4; r++) {
                    int row = row0 + mh * 32 + mt * 16 + q * 4 + r;
                    qb[row * 128 + cl] = (__bf16)((acc[mt][t][r] + bcv) * -1.44269504088896f);
                }
        }
    } else if (sp == 1) {
        // kb is now LINEAR (no swizzle): attn reads it directly from L2.
#pragma unroll
        for (int t = 0; t < 4; t++) {
            int d = clb + t * 16;
            float bcv = bc[128 + d];
#pragma unroll
            for (int mt = 0; mt < 2; mt++)
#pragma unroll
                for (int r = 0; r < 4; r++) {
                    int row = row0 + mh * 32 + mt * 16 + q * 4 + r;
                    kb[row * 128 + d] = (__bf16)(acc[mt][t][r] + bcv);
                }
        }
    } else {
        float wacc[2][4] = {{0, 0, 0, 0}, {0, 0, 0, 0}};
#pragma unroll
        for (int t = 0; t < 4; t++) {
            int cl = clb + t * 16;
            float bcv = bc[256 + cl];
            float wf = W_fc[cl];
#pragma unroll
            for (int mt = 0; mt < 2; mt++)
#pragma unroll
                for (int r = 0; r < 4; r++) wacc[mt][r] += (acc[mt][t][r] + bcv) * wf;
        }
        float vred[2][4];
#pragma unroll
        for (int mt = 0; mt < 2; mt++)
#pragma unroll
            for (int r = 0; r < 4; r++) {
                float v = wacc[mt][r];
                v += __shfl_xor(v, 1, 64);
                v += __shfl_xor(v, 2, 64);
                v += __shfl_xor(v, 4, 64);
                v += __shfl_xor(v, 8, 64);
                vred[mt][r] = v;
                if (nw == 0 && n16 == 0) wred[mh * 32 + mt * 16 + q * 4 + r] = v;
            }
        __syncthreads();
        if (nw == 1 && n16 == 0) {
#pragma unroll
            for (int mt = 0; mt < 2; mt++)
#pragma unroll
                for (int r = 0; r < 4; r++) {
                    int lr = mh * 32 + mt * 16 + q * 4 + r;
                    wv[row0 + lr] = wred[lr] + vred[mt][r];
                }
        }
    }
}

// ---- kernel 2: partial[sp][i] = sum_{j in slice sp} sigmoid(q_i.k_j) * wv_j ----
// Staging-free: kb/wv are L2-resident (FETCH_SIZE showed ~0 HBM traffic), so
// K fragments are loaded DIRECTLY from global into MFMA B-operands - no LDS
// staging, no wbuf, no per-chunk barriers; waves run free and latency hides
// via TLP (16 waves/CU). Block = 4 waves: 2 row-groups x 2 k-halves; the two
// k-halves of each row-group combine via a 1KB LDS reduce at the end so the
// partial layout stays [8][16384]. XCD swizzle (sp = lin&7) pins each XCD's
// kb working set to one 512KB slice.
__launch_bounds__(256, 4)
__global__ void attn(const __bf16* __restrict__ qb, const __bf16* __restrict__ kb,
                     const float* __restrict__ wv, float* __restrict__ partial) {
    __shared__ float red[4][64];
    const int tid = threadIdx.x;
    const int wave = tid >> 6, lane = tid & 63;
    const int n16 = lane & 15, q = lane >> 4;
    const int w_r = wave >> 1, w_k = wave & 1;

    const int lin = blockIdx.y * gridDim.x + blockIdx.x;   // [0, 1024)
    const int sp = lin & 7, xb = lin >> 3;                 // sp -> XCD (round-robin)
    const int row0 = xb * 128 + w_r * 64;
    const int jbase = sp * 2048 + w_k * 1024;

    bf16x8 qf[4][4];
#pragma unroll
    for (int mt = 0; mt < 4; mt++)
#pragma unroll
        for (int ks = 0; ks < 4; ks++)
            qf[mt][ks] = *(const bf16x8*)(qb + (size_t)(row0 + mt * 16 + n16) * 128 + ks * 32 + q * 8);

    float acc[4][4] = {{0}, {0}, {0}, {0}};

    const __bf16* kp = kb + (size_t)(jbase + n16) * 128 + q * 8;
    const float* wp = wv + jbase + n16;

    for (int t = 0; t < 64; t++) {
        // B fragments straight from L2 (16 rows x 128 cols per step)
        bf16x8 bf[4];
#pragma unroll
        for (int ks = 0; ks < 4; ks++)
            bf[ks] = *(const bf16x8*)(kp + (size_t)t * 16 * 128 + ks * 32);
        float wval = wp[t * 16];

        f32x4 s[4];
#pragma unroll
        for (int mt = 0; mt < 4; mt++) s[mt] = (f32x4){0, 0, 0, 0};
#pragma unroll
        for (int ks = 0; ks < 4; ks++) {
#pragma unroll
            for (int mt = 0; mt < 4; mt++)
                s[mt] = __builtin_amdgcn_mfma_f32_16x16x32_bf16(qf[mt][ks], bf[ks], s[mt], 0, 0, 0);
        }
#pragma unroll
        for (int mt = 0; mt < 4; mt++)
#pragma unroll
            for (int r = 0; r < 4; r++)
                // qb pre-scaled by -log2e: sigmoid(s) = rcp(1 + exp2(s'))
                acc[mt][r] += __builtin_amdgcn_rcpf(1.0f + __builtin_amdgcn_exp2f(s[mt][r])) * wval;
    }

    // reduce over the 16 k-lanes (n16 group), then across the 2 k-half waves
#pragma unroll
    for (int mt = 0; mt < 4; mt++)
#pragma unroll
        for (int r = 0; r < 4; r++) {
            float v = acc[mt][r];
            v += __shfl_xor(v, 1, 64);
            v += __shfl_xor(v, 2, 64);
            v += __shfl_xor(v, 4, 64);
            v += __shfl_xor(v, 8, 64);
            if (n16 == 0) red[wave][mt * 16 + q * 4 + r] = v;
        }
    __syncthreads();
    if (tid < 128) {
        int g = tid >> 6, l = tid & 63;
        partial[sp * N_ROWS + xb * 128 + g * 64 + l] = red[g * 2][l] + red[g * 2 + 1][l];
    }
}

// ---- kernel 3: deterministic reduce over 8 slices + b_fc ----
__global__ void reduce_out(const float* __restrict__ partial, const float* __restrict__ b_fc,
                           float* __restrict__ out) {
    int i = blockIdx.x * 256 + threadIdx.x;
    float v = b_fc[0];
#pragma unroll
    for (int s = 0; s < 8; s++) v += partial[s * N_ROWS + i];
    out[i] = v;
}

extern "C" void kernel_launch(void* const* d_in, const int* in_sizes, int n_in,
                              void* d_out, int out_size, void* d_ws, size_t ws_size,
                              hipStream_t stream) {
    const float* x       = (const float*)d_in[0];
    // d_in[1] = decay_value (unused by reference)
    const float* W_token = (const float*)d_in[2];
    const float* b_token = (const float*)d_in[3];
    const float* W_qkv   = (const float*)d_in[4];
    const float* b_qkv   = (const float*)d_in[5];
    const float* W_fc    = (const float*)d_in[6];
    const float* b_fc    = (const float*)d_in[7];
    float* out = (float*)d_out;
    char* ws = (char*)d_ws;

    __bf16* WcS = (__bf16*)(ws + OFF_WCS);
    float*  bc  = (float*)(ws + OFF_BC);
    __bf16* qb  = (__bf16*)(ws + OFF_QB);
    __bf16* kb  = (__bf16*)(ws + OFF_KB);
    float*  wv  = (float*)(ws + OFF_WV);
    float*  part = (float*)(ws + OFF_PART);

    prep<<<288, 256, 0, stream>>>(W_token, W_qkv, b_token, b_qkv, WcS, bc);
    gemm_qkv<<<dim3(256, 3), 256, 0, stream>>>(x, WcS, bc, W_fc, qb, kb, wv);
    attn<<<dim3(128, 8), 256, 0, stream>>>(qb, kb, wv, part);
    reduce_out<<<64, 256, 0, stream>>>(part, b_fc, out);
}

// Round 4
// 203.842 us; speedup vs baseline: 1.2194x; 1.2194x over previous
//
#include <hip/hip_runtime.h>
#include <hip/hip_bf16.h>
#include <stdint.h>

#define N_ROWS 16384

typedef __bf16 bf16x8 __attribute__((ext_vector_type(8)));
typedef float f32x4 __attribute__((ext_vector_type(4)));

#define AS1 __attribute__((address_space(1)))
#define AS3 __attribute__((address_space(3)))

// ---------------- ws layout (bytes) ----------------
// WcS : (W_token@W_qkv)^T bf16 [384][768], 8-elt chunks XOR-swizzled   589824
// bc  : f32 [384]  (b_token@W_qkv + b_qkv)                               1536
// qb  : bf16 [16384][128]  (q * -log2e)                               4194304
// kb  : bf16 [16384][128]  (XOR-swizzled, staged via global_load_lds) 4194304
// wv  : f32  [16384]  ((v+bias) . W_fc)                                 65536
// part: f32  [8][16384]                                                524288
#define OFF_WCS  0u
#define OFF_BC   589824u
#define OFF_QB   591360u
#define OFF_KB   4785664u
#define OFF_WV   8979968u
#define OFF_PART 9045504u

// ---- kernel 0: Wc = W_token @ W_qkv -> bf16, [n][768] with 8-elt chunk XOR swizzle;
//      bc = b_token @ W_qkv + b_qkv ----
__global__ void prep(const float* __restrict__ Wt, const float* __restrict__ Wq,
                     const float* __restrict__ bt, const float* __restrict__ bq,
                     __bf16* __restrict__ WcS, float* __restrict__ bc) {
    int u = blockIdx.x * 256 + threadIdx.x;          // [0, 768*96)
    if (u < 768 * 96) {
        int k = u / 96, n4 = u % 96;
        float s[4] = {0, 0, 0, 0};
        const float* wtp = Wt + k * 128;
        const float* wqp = Wq + n4 * 4;
#pragma unroll 8
        for (int d = 0; d < 128; d++) {
            float a = wtp[d];
            float4 b = *(const float4*)(wqp + d * 384);
            s[0] += a * b.x; s[1] += a * b.y; s[2] += a * b.z; s[3] += a * b.w;
        }
        int kb_ = k >> 6, c = (k >> 3) & 7, k7 = k & 7;
#pragma unroll
        for (int j = 0; j < 4; j++) {
            int n = n4 * 4 + j;
            WcS[n * 768 + kb_ * 64 + ((c ^ (n & 7)) << 3) + k7] = (__bf16)s[j];
        }
    }
    if (u < 384) {
        float s = bq[u];
        for (int d = 0; d < 128; d++) s += bt[d] * Wq[d * 384 + u];
        bc[u] = s;
    }
}

// ---- kernel 1: qkv = bf16(x) @ Wc + bc via LDS-staged tiled GEMM ----
// BM=64, BN=128, BK=64; grid (256, 3); sp aligns with q / k / v+wv epilogues.
__launch_bounds__(256)
__global__ void gemm_qkv(const float* __restrict__ x, const __bf16* __restrict__ WcS,
                         const float* __restrict__ bc, const float* __restrict__ W_fc,
                         __bf16* __restrict__ qb, __bf16* __restrict__ kb,
                         float* __restrict__ wv) {
    __shared__ float  Asm[64 * 64];    // fp32 A tile, 32B-pair XOR-swizzled
    __shared__ __bf16 Bsm[128 * 64];   // bf16 B tile, 16B-chunk XOR-swizzled
    __shared__ float  wred[64];
    const int tid = threadIdx.x, wave = tid >> 6, lane = tid & 63;
    const int n16 = lane & 15, q = lane >> 4;
    const int mh = wave >> 1, nw = wave & 1;
    const int row0 = blockIdx.x * 64;
    const int sp = blockIdx.y;

    // per-lane staging source pointers (swizzle baked into the global address)
    const char* aptr[4];
    const char* bptr[4];
    {
        int p = (lane & 15) >> 1, half = lane & 1;
#pragma unroll
        for (int i = 0; i < 4; i++) {
            int ar = row0 + wave * 16 + i * 4 + (lane >> 4);
            aptr[i] = (const char*)x + (size_t)ar * 3072 + ((p ^ (ar & 7)) * 8 + half * 4) * 4;
            int br = sp * 128 + wave * 32 + i * 8 + (lane >> 3);
            bptr[i] = (const char*)WcS + (size_t)br * 1536 + (lane & 7) * 16;
        }
    }
    f32x4 acc[2][4];
#pragma unroll
    for (int mt = 0; mt < 2; mt++)
#pragma unroll
        for (int t = 0; t < 4; t++) acc[mt][t] = (f32x4){0, 0, 0, 0};

    for (int kbi = 0; kbi < 12; kbi++) {
#pragma unroll
        for (int i = 0; i < 4; i++)
            __builtin_amdgcn_global_load_lds((const AS1 void*)(aptr[i] + kbi * 256),
                (AS3 void*)((char*)Asm + wave * 4096 + i * 1024), 16, 0, 0);
#pragma unroll
        for (int i = 0; i < 4; i++)
            __builtin_amdgcn_global_load_lds((const AS1 void*)(bptr[i] + kbi * 128),
                (AS3 void*)((char*)Bsm + wave * 4096 + i * 1024), 16, 0, 0);
        __syncthreads();
#pragma unroll
        for (int ks = 0; ks < 2; ks++) {
            const int swz = ((ks * 4 + q) ^ (n16 & 7)) << 3;
            bf16x8 af[2];
#pragma unroll
            for (int mt = 0; mt < 2; mt++) {
                const float* ap = Asm + (mh * 32 + mt * 16 + n16) * 64 + swz;
                f32x4 a0 = *(const f32x4*)ap;
                f32x4 a1 = *(const f32x4*)(ap + 4);
                bf16x8 t;
                t[0] = (__bf16)a0[0]; t[1] = (__bf16)a0[1]; t[2] = (__bf16)a0[2]; t[3] = (__bf16)a0[3];
                t[4] = (__bf16)a1[0]; t[5] = (__bf16)a1[1]; t[6] = (__bf16)a1[2]; t[7] = (__bf16)a1[3];
                af[mt] = t;
            }
#pragma unroll
            for (int t = 0; t < 4; t++) {
                bf16x8 bf = *(const bf16x8*)(Bsm + (nw * 64 + t * 16 + n16) * 64 + swz);
                acc[0][t] = __builtin_amdgcn_mfma_f32_16x16x32_bf16(af[0], bf, acc[0][t], 0, 0, 0);
                acc[1][t] = __builtin_amdgcn_mfma_f32_16x16x32_bf16(af[1], bf, acc[1][t], 0, 0, 0);
            }
        }
        __syncthreads();
    }

    // epilogue: cols of this block = sp*128 + nw*64 + t*16 + n16
    const int clb = nw * 64 + n16;
    if (sp == 0) {
#pragma unroll
        for (int t = 0; t < 4; t++) {
            int cl = clb + t * 16;
            float bcv = bc[cl];
#pragma unroll
            for (int mt = 0; mt < 2; mt++)
#pragma unroll
                for (int r = 0; r < 4; r++) {
                    int row = row0 + mh * 32 + mt * 16 + q * 4 + r;
                    qb[row * 128 + cl] = (__bf16)((acc[mt][t][r] + bcv) * -1.44269504088896f);
                }
        }
    } else if (sp == 1) {
        // kb XOR-swizzled (16-chunk index ^ row&15) so attn's linear
        // global_load_lds + swizzled ds_read is bank-conflict-free.
#pragma unroll
        for (int t = 0; t < 4; t++) {
            int d = clb + t * 16;
            float bcv = bc[128 + d];
#pragma unroll
            for (int mt = 0; mt < 2; mt++)
#pragma unroll
                for (int r = 0; r < 4; r++) {
                    int row = row0 + mh * 32 + mt * 16 + q * 4 + r;
                    kb[row * 128 + (((d >> 3) ^ (row & 15)) << 3) + (d & 7)] = (__bf16)(acc[mt][t][r] + bcv);
                }
        }
    } else {
        float wacc[2][4] = {{0, 0, 0, 0}, {0, 0, 0, 0}};
#pragma unroll
        for (int t = 0; t < 4; t++) {
            int cl = clb + t * 16;
            float bcv = bc[256 + cl];
            float wf = W_fc[cl];
#pragma unroll
            for (int mt = 0; mt < 2; mt++)
#pragma unroll
                for (int r = 0; r < 4; r++) wacc[mt][r] += (acc[mt][t][r] + bcv) * wf;
        }
        float vred[2][4];
#pragma unroll
        for (int mt = 0; mt < 2; mt++)
#pragma unroll
            for (int r = 0; r < 4; r++) {
                float v = wacc[mt][r];
                v += __shfl_xor(v, 1, 64);
                v += __shfl_xor(v, 2, 64);
                v += __shfl_xor(v, 4, 64);
                v += __shfl_xor(v, 8, 64);
                vred[mt][r] = v;
                if (nw == 0 && n16 == 0) wred[mh * 32 + mt * 16 + q * 4 + r] = v;
            }
        __syncthreads();
        if (nw == 1 && n16 == 0) {
#pragma unroll
            for (int mt = 0; mt < 2; mt++)
#pragma unroll
                for (int r = 0; r < 4; r++) {
                    int lr = mh * 32 + mt * 16 + q * 4 + r;
                    wv[row0 + lr] = wred[lr] + vred[mt][r];
                }
        }
    }
}

// ---- kernel 2: partial[sp][i] = sum_{j in slice sp} sigmoid(q_i.k_j) * wv_j ----
// T3+T4 counted-vmcnt pipeline (NO vmcnt(0) drain anywhere in the loop):
//   4-deep ring of 32-row K chunks (4 x 8 KB LDS); per iter:
//   issue(jc+2) -> s_waitcnt vmcnt(4) -> raw s_barrier -> compute(jc).
//   2 chunks of staging latency always in flight; one barrier per chunk.
//   Safety: issue target slot (jc+2)&3 was last read at compute(jc-2); the
//   barrier guarantees the slowest wave is at worst in compute(jc-1).
// Block = 4 waves x 32 q-rows = 128 rows; all waves share the K ring (4x reuse).
// Grid = 1024 blocks 1D; sp = bid&7 pins each k-slice (512 KB) to one XCD's L2.
__launch_bounds__(256, 4)
__global__ void attn(const __bf16* __restrict__ qb, const __bf16* __restrict__ kb,
                     const float* __restrict__ wv, float* __restrict__ partial) {
    __shared__ __bf16 kbuf[4 * 32 * 128];   // 32 KB ring
    const int tid = threadIdx.x;
    const int wave = tid >> 6, lane = tid & 63;
    const int n16 = lane & 15, q = lane >> 4;
    const int bid = blockIdx.x;
    const int sp = bid & 7;                  // XCD-pinned k-slice
    const int rb = bid >> 3;                 // [0,128) row block
    const int row0 = rb * 128 + wave * 32;
    const int jb0 = sp * 2048;

    // q fragments: 32 rows x 128 d, resident in 32 VGPRs
    bf16x8 qf[2][4];
#pragma unroll
    for (int mt = 0; mt < 2; mt++)
#pragma unroll
        for (int ks = 0; ks < 4; ks++)
            qf[mt][ks] = *(const bf16x8*)(qb + (size_t)(row0 + mt * 16 + n16) * 128 + ks * 32 + q * 8);

    float acc[2][4] = {{0}, {0}};

    // each wave stages 2 KB (2 x 1 KB loads) of each 8 KB chunk
#define ISSUE(c, slot)                                                                  \
    {                                                                                   \
        const char* gsrc = (const char*)kb + (size_t)(jb0 + (c) * 32) * 256 + wave * 2048; \
        char* gdst = (char*)kbuf + (slot) * 8192 + wave * 2048;                          \
        __builtin_amdgcn_global_load_lds((const AS1 void*)(gsrc + lane * 16),            \
                                         (AS3 void*)gdst, 16, 0, 0);                     \
        __builtin_amdgcn_global_load_lds((const AS1 void*)(gsrc + 1024 + lane * 16),     \
                                         (AS3 void*)(gdst + 1024), 16, 0, 0);            \
    }

    // prologue: chunks 0,1 in flight
    ISSUE(0, 0);
    ISSUE(1, 1);

    for (int jc = 0; jc < 64; jc++) {
        // prefetch 2 ahead; tail re-stages chunk 63 into dead slots (keeps vmcnt uniform)
        const int jn = (jc + 2 < 64) ? jc + 2 : 63;
        ISSUE(jn, (jc + 2) & 3);

        // wait for chunk jc's loads (4 newer staging loads stay in flight),
        // then raw barrier (does NOT drain vmcnt) so all waves' loads are in.
        asm volatile("s_waitcnt vmcnt(4)" ::: "memory");
        __builtin_amdgcn_sched_barrier(0);
        __builtin_amdgcn_s_barrier();

        const __bf16* curK = kbuf + (jc & 3) * 4096;
#pragma unroll
        for (int t = 0; t < 2; t++) {
            f32x4 s0 = (f32x4){0, 0, 0, 0}, s1 = (f32x4){0, 0, 0, 0};
#pragma unroll
            for (int ks = 0; ks < 4; ks++) {
                const int chunk = (ks * 4 + q) ^ n16;   // undo the global-side swizzle
                bf16x8 bf = *(const bf16x8*)(curK + (t * 16 + n16) * 128 + chunk * 8);
                s0 = __builtin_amdgcn_mfma_f32_16x16x32_bf16(qf[0][ks], bf, s0, 0, 0, 0);
                s1 = __builtin_amdgcn_mfma_f32_16x16x32_bf16(qf[1][ks], bf, s1, 0, 0, 0);
            }
            const float wval = wv[jb0 + jc * 32 + t * 16 + n16];
#pragma unroll
            for (int r = 0; r < 4; r++) {
                // qb pre-scaled by -log2e: sigmoid(s) = rcp(1 + exp2(s'))
                acc[0][r] += __builtin_amdgcn_rcpf(1.0f + __builtin_amdgcn_exp2f(s0[r])) * wval;
                acc[1][r] += __builtin_amdgcn_rcpf(1.0f + __builtin_amdgcn_exp2f(s1[r])) * wval;
            }
        }
    }
#undef ISSUE

    // per-wave reduction over the 16 k-lanes; rows unique per wave -> direct store
#pragma unroll
    for (int mt = 0; mt < 2; mt++)
#pragma unroll
        for (int r = 0; r < 4; r++) {
            float v = acc[mt][r];
            v += __shfl_xor(v, 1, 64);
            v += __shfl_xor(v, 2, 64);
            v += __shfl_xor(v, 4, 64);
            v += __shfl_xor(v, 8, 64);
            if (n16 == 0) partial[sp * N_ROWS + row0 + mt * 16 + q * 4 + r] = v;
        }
}

// ---- kernel 3: deterministic reduce over 8 slices + b_fc ----
__global__ void reduce_out(const float* __restrict__ partial, const float* __restrict__ b_fc,
                           float* __restrict__ out) {
    int i = blockIdx.x * 256 + threadIdx.x;
    float v = b_fc[0];
#pragma unroll
    for (int s = 0; s < 8; s++) v += partial[s * N_ROWS + i];
    out[i] = v;
}

extern "C" void kernel_launch(void* const* d_in, const int* in_sizes, int n_in,
                              void* d_out, int out_size, void* d_ws, size_t ws_size,
                              hipStream_t stream) {
    const float* x       = (const float*)d_in[0];
    // d_in[1] = decay_value (unused by reference)
    const float* W_token = (const float*)d_in[2];
    const float* b_token = (const float*)d_in[3];
    const float* W_qkv   = (const float*)d_in[4];
    const float* b_qkv   = (const float*)d_in[5];
    const float* W_fc    = (const float*)d_in[6];
    const float* b_fc    = (const float*)d_in[7];
    float* out = (float*)d_out;
    char* ws = (char*)d_ws;

    __bf16* WcS = (__bf16*)(ws + OFF_WCS);
    float*  bc  = (float*)(ws + OFF_BC);
    __bf16* qb  = (__bf16*)(ws + OFF_QB);
    __bf16* kb  = (__bf16*)(ws + OFF_KB);
    float*  wv  = (float*)(ws + OFF_WV);
    float*  part = (float*)(ws + OFF_PART);

    prep<<<288, 256, 0, stream>>>(W_token, W_qkv, b_token, b_qkv, WcS, bc);
    gemm_qkv<<<dim3(256, 3), 256, 0, stream>>>(x, WcS, bc, W_fc, qb, kb, wv);
    attn<<<1024, 256, 0, stream>>>(qb, kb, wv, part);
    reduce_out<<<64, 256, 0, stream>>>(part, b_fc, out);
}

// Round 5
// 202.930 us; speedup vs baseline: 1.2249x; 1.0045x over previous
//
#include <hip/hip_runtime.h>
#include <hip/hip_bf16.h>
#include <stdint.h>

#define N_ROWS 16384

typedef __bf16 bf16x8 __attribute__((ext_vector_type(8)));
typedef float f32x4 __attribute__((ext_vector_type(4)));

#define AS1 __attribute__((address_space(1)))
#define AS3 __attribute__((address_space(3)))

// ---------------- ws layout (bytes) ----------------
// WcS : (W_token@W_qkv)^T bf16 [384][768], 8-elt chunks XOR-swizzled   589824
// bc  : f32 [384]  (b_token@W_qkv + b_qkv)                               1536
// qb  : bf16 [16384][128]  (q * -log2e)                               4194304
// kb  : bf16 [16384][128]  (XOR-swizzled, staged via global_load_lds) 4194304
// wv  : f32  [16384]  ((v+bias) . W_fc)                                 65536
// part: f32  [8][16384]                                                524288
#define OFF_WCS  0u
#define OFF_BC   589824u
#define OFF_QB   591360u
#define OFF_KB   4785664u
#define OFF_WV   8979968u
#define OFF_PART 9045504u

// ---- kernel 0: Wc = W_token @ W_qkv -> bf16, [n][768] with 8-elt chunk XOR swizzle;
//      bc = b_token @ W_qkv + b_qkv ----
__global__ void prep(const float* __restrict__ Wt, const float* __restrict__ Wq,
                     const float* __restrict__ bt, const float* __restrict__ bq,
                     __bf16* __restrict__ WcS, float* __restrict__ bc) {
    int u = blockIdx.x * 256 + threadIdx.x;          // [0, 768*96)
    if (u < 768 * 96) {
        int k = u / 96, n4 = u % 96;
        float s[4] = {0, 0, 0, 0};
        const float* wtp = Wt + k * 128;
        const float* wqp = Wq + n4 * 4;
#pragma unroll 8
        for (int d = 0; d < 128; d++) {
            float a = wtp[d];
            float4 b = *(const float4*)(wqp + d * 384);
            s[0] += a * b.x; s[1] += a * b.y; s[2] += a * b.z; s[3] += a * b.w;
        }
        int kb_ = k >> 6, c = (k >> 3) & 7, k7 = k & 7;
#pragma unroll
        for (int j = 0; j < 4; j++) {
            int n = n4 * 4 + j;
            WcS[n * 768 + kb_ * 64 + ((c ^ (n & 7)) << 3) + k7] = (__bf16)s[j];
        }
    }
    if (u < 384) {
        float s = bq[u];
        for (int d = 0; d < 128; d++) s += bt[d] * Wq[d * 384 + u];
        bc[u] = s;
    }
}

// ---- kernel 1: qkv = bf16(x) @ Wc + bc via LDS-staged tiled GEMM ----
// BM=64, BN=128, BK=64; grid (256, 3); sp aligns with q / k / v+wv epilogues.
__launch_bounds__(256)
__global__ void gemm_qkv(const float* __restrict__ x, const __bf16* __restrict__ WcS,
                         const float* __restrict__ bc, const float* __restrict__ W_fc,
                         __bf16* __restrict__ qb, __bf16* __restrict__ kb,
                         float* __restrict__ wv) {
    __shared__ float  Asm[64 * 64];    // fp32 A tile, 32B-pair XOR-swizzled
    __shared__ __bf16 Bsm[128 * 64];   // bf16 B tile, 16B-chunk XOR-swizzled
    __shared__ float  wred[64];
    const int tid = threadIdx.x, wave = tid >> 6, lane = tid & 63;
    const int n16 = lane & 15, q = lane >> 4;
    const int mh = wave >> 1, nw = wave & 1;
    const int row0 = blockIdx.x * 64;
    const int sp = blockIdx.y;

    // per-lane staging source pointers (swizzle baked into the global address)
    const char* aptr[4];
    const char* bptr[4];
    {
        int p = (lane & 15) >> 1, half = lane & 1;
#pragma unroll
        for (int i = 0; i < 4; i++) {
            int ar = row0 + wave * 16 + i * 4 + (lane >> 4);
            aptr[i] = (const char*)x + (size_t)ar * 3072 + ((p ^ (ar & 7)) * 8 + half * 4) * 4;
            int br = sp * 128 + wave * 32 + i * 8 + (lane >> 3);
            bptr[i] = (const char*)WcS + (size_t)br * 1536 + (lane & 7) * 16;
        }
    }
    f32x4 acc[2][4];
#pragma unroll
    for (int mt = 0; mt < 2; mt++)
#pragma unroll
        for (int t = 0; t < 4; t++) acc[mt][t] = (f32x4){0, 0, 0, 0};

    for (int kbi = 0; kbi < 12; kbi++) {
#pragma unroll
        for (int i = 0; i < 4; i++)
            __builtin_amdgcn_global_load_lds((const AS1 void*)(aptr[i] + kbi * 256),
                (AS3 void*)((char*)Asm + wave * 4096 + i * 1024), 16, 0, 0);
#pragma unroll
        for (int i = 0; i < 4; i++)
            __builtin_amdgcn_global_load_lds((const AS1 void*)(bptr[i] + kbi * 128),
                (AS3 void*)((char*)Bsm + wave * 4096 + i * 1024), 16, 0, 0);
        __syncthreads();
#pragma unroll
        for (int ks = 0; ks < 2; ks++) {
            const int swz = ((ks * 4 + q) ^ (n16 & 7)) << 3;
            bf16x8 af[2];
#pragma unroll
            for (int mt = 0; mt < 2; mt++) {
                const float* ap = Asm + (mh * 32 + mt * 16 + n16) * 64 + swz;
                f32x4 a0 = *(const f32x4*)ap;
                f32x4 a1 = *(const f32x4*)(ap + 4);
                bf16x8 t;
                t[0] = (__bf16)a0[0]; t[1] = (__bf16)a0[1]; t[2] = (__bf16)a0[2]; t[3] = (__bf16)a0[3];
                t[4] = (__bf16)a1[0]; t[5] = (__bf16)a1[1]; t[6] = (__bf16)a1[2]; t[7] = (__bf16)a1[3];
                af[mt] = t;
            }
#pragma unroll
            for (int t = 0; t < 4; t++) {
                bf16x8 bf = *(const bf16x8*)(Bsm + (nw * 64 + t * 16 + n16) * 64 + swz);
                acc[0][t] = __builtin_amdgcn_mfma_f32_16x16x32_bf16(af[0], bf, acc[0][t], 0, 0, 0);
                acc[1][t] = __builtin_amdgcn_mfma_f32_16x16x32_bf16(af[1], bf, acc[1][t], 0, 0, 0);
            }
        }
        __syncthreads();
    }

    // epilogue: cols of this block = sp*128 + nw*64 + t*16 + n16
    const int clb = nw * 64 + n16;
    if (sp == 0) {
#pragma unroll
        for (int t = 0; t < 4; t++) {
            int cl = clb + t * 16;
            float bcv = bc[cl];
#pragma unroll
            for (int mt = 0; mt < 2; mt++)
#pragma unroll
                for (int r = 0; r < 4; r++) {
                    int row = row0 + mh * 32 + mt * 16 + q * 4 + r;
                    qb[row * 128 + cl] = (__bf16)((acc[mt][t][r] + bcv) * -1.44269504088896f);
                }
        }
    } else if (sp == 1) {
        // kb XOR-swizzled (16-chunk index ^ row&15) so attn's linear
        // global_load_lds + swizzled ds_read is bank-conflict-free.
#pragma unroll
        for (int t = 0; t < 4; t++) {
            int d = clb + t * 16;
            float bcv = bc[128 + d];
#pragma unroll
            for (int mt = 0; mt < 2; mt++)
#pragma unroll
                for (int r = 0; r < 4; r++) {
                    int row = row0 + mh * 32 + mt * 16 + q * 4 + r;
                    kb[row * 128 + (((d >> 3) ^ (row & 15)) << 3) + (d & 7)] = (__bf16)(acc[mt][t][r] + bcv);
                }
        }
    } else {
        float wacc[2][4] = {{0, 0, 0, 0}, {0, 0, 0, 0}};
#pragma unroll
        for (int t = 0; t < 4; t++) {
            int cl = clb + t * 16;
            float bcv = bc[256 + cl];
            float wf = W_fc[cl];
#pragma unroll
            for (int mt = 0; mt < 2; mt++)
#pragma unroll
                for (int r = 0; r < 4; r++) wacc[mt][r] += (acc[mt][t][r] + bcv) * wf;
        }
        float vred[2][4];
#pragma unroll
        for (int mt = 0; mt < 2; mt++)
#pragma unroll
            for (int r = 0; r < 4; r++) {
                float v = wacc[mt][r];
                v += __shfl_xor(v, 1, 64);
                v += __shfl_xor(v, 2, 64);
                v += __shfl_xor(v, 4, 64);
                v += __shfl_xor(v, 8, 64);
                vred[mt][r] = v;
                if (nw == 0 && n16 == 0) wred[mh * 32 + mt * 16 + q * 4 + r] = v;
            }
        __syncthreads();
        if (nw == 1 && n16 == 0) {
#pragma unroll
            for (int mt = 0; mt < 2; mt++)
#pragma unroll
                for (int r = 0; r < 4; r++) {
                    int lr = mh * 32 + mt * 16 + q * 4 + r;
                    wv[row0 + lr] = wred[lr] + vred[mt][r];
                }
        }
    }
}

// ---- kernel 2: partial[sp][i] = sum_{j in slice sp} sigmoid(q_i.k_j) * wv_j ----
// T3+T4 counted-vmcnt pipeline, CLEAN this round: the ONLY in-loop vmem ops are
// the 2 staging global_load_lds per chunk (wv slice pre-staged to LDS in the
// prologue, consumed via ds_read), so `s_waitcnt vmcnt(4)` really does keep 2
// chunks in flight with no compiler-inserted drains. ds_read addresses hoisted:
// 4 per-lane swizzled bases + compile-time slot/t immediate offsets (jc
// unrolled by 4). s_setprio(1) wraps the MFMA cluster (T5).
// Block = 4 waves x 32 q-rows; grid 1024; sp = bid&7 pins k-slice to one XCD.
__launch_bounds__(256, 4)
__global__ void attn(const __bf16* __restrict__ qb, const __bf16* __restrict__ kb,
                     const float* __restrict__ wv, float* __restrict__ partial) {
    __shared__ __bf16 kbuf[4 * 32 * 128];   // 32 KB ring
    __shared__ float wlds[2048];            // 8 KB: this sp's whole wv slice
    const int tid = threadIdx.x;
    const int wave = tid >> 6, lane = tid & 63;
    const int n16 = lane & 15, q = lane >> 4;
    const int bid = blockIdx.x;
    const int sp = bid & 7;                  // XCD-pinned k-slice
    const int rb = bid >> 3;                 // [0,128) row block
    const int row0 = rb * 128 + wave * 32;
    const int jb0 = sp * 2048;

    // q fragments: 32 rows x 128 d, resident in 32 VGPRs (issued first; the
    // first in-loop vmcnt(4) drains them along with wv/chunk0)
    bf16x8 qf[2][4];
#pragma unroll
    for (int mt = 0; mt < 2; mt++)
#pragma unroll
        for (int ks = 0; ks < 4; ks++)
            qf[mt][ks] = *(const bf16x8*)(qb + (size_t)(row0 + mt * 16 + n16) * 128 + ks * 32 + q * 8);
    __builtin_amdgcn_sched_barrier(0);   // keep qf loads ahead of the staging queue

    // prologue staging, oldest-first so vmcnt(4) drains in order:
    // wv slice (2 loads), chunk 0 (2), chunk 1 (2)
    {
        const char* wsrc = (const char*)(wv + jb0) + tid * 16;
        char* wdst = (char*)wlds + tid * 16;
        __builtin_amdgcn_global_load_lds((const AS1 void*)wsrc, (AS3 void*)wdst, 16, 0, 0);
        __builtin_amdgcn_global_load_lds((const AS1 void*)(wsrc + 4096),
                                         (AS3 void*)(wdst + 4096), 16, 0, 0);
    }

    // each wave stages 2 KB (2 x 1 KB loads) of each 8 KB chunk
#define ISSUE(c, slot)                                                                  \
    {                                                                                   \
        const char* gsrc = (const char*)kb + (size_t)(jb0 + (c) * 32) * 256 + wave * 2048; \
        char* gdst = (char*)kbuf + (slot) * 8192 + wave * 2048;                          \
        __builtin_amdgcn_global_load_lds((const AS1 void*)(gsrc + lane * 16),            \
                                         (AS3 void*)gdst, 16, 0, 0);                     \
        __builtin_amdgcn_global_load_lds((const AS1 void*)(gsrc + 1024 + lane * 16),     \
                                         (AS3 void*)(gdst + 1024), 16, 0, 0);            \
    }

    ISSUE(0, 0);
    ISSUE(1, 1);

    float acc[2][4] = {{0}, {0}};

    // per-lane swizzled ds_read bases (elements); slot/t become imm offsets
    const __bf16* kaddr[4];
#pragma unroll
    for (int ks = 0; ks < 4; ks++)
        kaddr[ks] = kbuf + n16 * 128 + (((ks * 4 + q) ^ n16) << 3);
    const float* wbase = wlds + n16;

#pragma unroll 4
    for (int jc = 0; jc < 64; jc++) {
        // prefetch 2 ahead; tail re-stages chunk 63 into dead slots (keeps vmcnt uniform)
        const int jn = (jc + 2 < 64) ? jc + 2 : 63;
        ISSUE(jn, (jc + 2) & 3);

        // wait for chunk jc's loads (4 newer staging loads stay in flight),
        // then raw barrier (does NOT drain vmcnt) so all waves' loads are in.
        asm volatile("s_waitcnt vmcnt(4)" ::: "memory");
        __builtin_amdgcn_sched_barrier(0);
        __builtin_amdgcn_s_barrier();

        const int slot = jc & 3;   // compile-time under unroll-4
#pragma unroll
        for (int t = 0; t < 2; t++) {
            f32x4 s0 = (f32x4){0, 0, 0, 0}, s1 = (f32x4){0, 0, 0, 0};
            __builtin_amdgcn_s_setprio(1);
#pragma unroll
            for (int ks = 0; ks < 4; ks++) {
                bf16x8 bf = *(const bf16x8*)(kaddr[ks] + slot * 4096 + t * 2048);
                s0 = __builtin_amdgcn_mfma_f32_16x16x32_bf16(qf[0][ks], bf, s0, 0, 0, 0);
                s1 = __builtin_amdgcn_mfma_f32_16x16x32_bf16(qf[1][ks], bf, s1, 0, 0, 0);
            }
            __builtin_amdgcn_s_setprio(0);
            const float wval = wbase[jc * 32 + t * 16];   // ds_read, broadcast per n16
#pragma unroll
            for (int r = 0; r < 4; r++) {
                // qb pre-scaled by -log2e: sigmoid(s) = rcp(1 + exp2(s'))
                acc[0][r] += __builtin_amdgcn_rcpf(1.0f + __builtin_amdgcn_exp2f(s0[r])) * wval;
                acc[1][r] += __builtin_amdgcn_rcpf(1.0f + __builtin_amdgcn_exp2f(s1[r])) * wval;
            }
        }
    }
#undef ISSUE

    // per-wave reduction over the 16 k-lanes; rows unique per wave -> direct store
#pragma unroll
    for (int mt = 0; mt < 2; mt++)
#pragma unroll
        for (int r = 0; r < 4; r++) {
            float v = acc[mt][r];
            v += __shfl_xor(v, 1, 64);
            v += __shfl_xor(v, 2, 64);
            v += __shfl_xor(v, 4, 64);
            v += __shfl_xor(v, 8, 64);
            if (n16 == 0) partial[sp * N_ROWS + row0 + mt * 16 + q * 4 + r] = v;
        }
}

// ---- kernel 3: deterministic reduce over 8 slices + b_fc ----
__global__ void reduce_out(const float* __restrict__ partial, const float* __restrict__ b_fc,
                           float* __restrict__ out) {
    int i = blockIdx.x * 256 + threadIdx.x;
    float v = b_fc[0];
#pragma unroll
    for (int s = 0; s < 8; s++) v += partial[s * N_ROWS + i];
    out[i] = v;
}

extern "C" void kernel_launch(void* const* d_in, const int* in_sizes, int n_in,
                              void* d_out, int out_size, void* d_ws, size_t ws_size,
                              hipStream_t stream) {
    const float* x       = (const float*)d_in[0];
    // d_in[1] = decay_value (unused by reference)
    const float* W_token = (const float*)d_in[2];
    const float* b_token = (const float*)d_in[3];
    const float* W_qkv   = (const float*)d_in[4];
    const float* b_qkv   = (const float*)d_in[5];
    const float* W_fc    = (const float*)d_in[6];
    const float* b_fc    = (const float*)d_in[7];
    float* out = (float*)d_out;
    char* ws = (char*)d_ws;

    __bf16* WcS = (__bf16*)(ws + OFF_WCS);
    float*  bc  = (float*)(ws + OFF_BC);
    __bf16* qb  = (__bf16*)(ws + OFF_QB);
    __bf16* kb  = (__bf16*)(ws + OFF_KB);
    float*  wv  = (float*)(ws + OFF_WV);
    float*  part = (float*)(ws + OFF_PART);

    prep<<<288, 256, 0, stream>>>(W_token, W_qkv, b_token, b_qkv, WcS, bc);
    gemm_qkv<<<dim3(256, 3), 256, 0, stream>>>(x, WcS, bc, W_fc, qb, kb, wv);
    attn<<<1024, 256, 0, stream>>>(qb, kb, wv, part);
    reduce_out<<<64, 256, 0, stream>>>(part, b_fc, out);
}